// Round 6
// baseline (322.595 us; speedup 1.0000x reference)
//
#include <hip/hip_runtime.h>
#include <math.h>

// SRP-PHAT via Chebyshev factorization (degree 32; tail ~1e-7 at z_max=14.67).
// G[bt, p*32+c] = sum_f Xnorm_{re|im}[bt,f,p] * coef_c(w_f*S), then
// Ys[bt,d] = sum_k G[bt,k] * Tt[k,d]. Diagonal mic pairs dropped.
// Round 12: stageA CNT 8->4 + sCall 48->44 rows: LDS/block 24576->14848 B ->
// static residency 6->11 blocks/CU (r11 measured occupancy 25.8% with all
// pipes <40% = stall-bound; LDS footprint was the occupancy cap). Work per
// thread unchanged (11 short chunks vs 6). DMA slot cut at e<288 keeps lane 0
// of each participating wave active -> wave-uniform LDS base still correct
// (m104). Everything else identical to the passing r11 kernel.

#define F_BINS  513
#define M_TOTAL 1000
#define D_TOTAL 2562
#define D_PAD   2688          // 42 * 64
#define NPAIR   28
#define NC      32
#define K2      (NPAIR * NC)  // 896
#define S_SCALE 4.67f         // |dtau| <= 4.665
#define NBT     4             // bt per stageA block
#define CNT     4             // f per stageA chunk
#define FSPLIT  12            // stageA f-splits
#define KSPB    4             // gemmB K-splits
#define KPS     224           // K2 / KSPB
#define BT_PAD  1024          // Gt row length (bt padded)
#define DBLK    11            // ceil(D_PAD/256) for k_init ttab part

// ws layout (float offsets); total 14,094,464 floats = 56.4 MB
#define OFF_COEF 0
#define OFF_TT   16512
#define OFF_GT   (OFF_TT + (size_t)K2 * D_PAD)            // 2,424,960
#define OFF_GP   (OFF_GT + (size_t)K2 * BT_PAD)           // 3,342,464
#define OFF_YS   OFF_GP   // Ysp (4 planes = 10,752,000) aliases Gp (12 planes, same)

__device__ __constant__ int c_ptab[NPAIR] = {1,2,3,4,5,6,7, 9,10,11,12,13,14,
                                             16,17,18,19,20, 22,23,24,25,
                                             27,28,29, 31,32, 34};
__device__ __constant__ int c_i0[NPAIR] = {0,0,0,0,0,0,0, 1,1,1,1,1,1,
                                           2,2,2,2,2, 3,3,3,3, 4,4,4, 5,5, 6};
__device__ __constant__ int c_i1[NPAIR] = {1,2,3,4,5,6,7, 2,3,4,5,6,7,
                                           3,4,5,6,7, 4,5,6,7, 5,6,7, 6,7, 7};

// ---- fused init: blocks [0, DBLK*NPAIR) build Tt; blocks [.., +513) build
// coefEO[f][32] (c<16 -> cos-coeff a_{2c}(z_f); c>=16 -> sin b_{2c'+1}).
__global__ void k_init(const float* __restrict__ taus,
                       float* __restrict__ coefEO, float* __restrict__ Tt) {
    __shared__ double sHC[NC][NC + 1];
    __shared__ double sHS[NC][NC + 1];
    if (blockIdx.x < DBLK * NPAIR) {
        // ---- Tt[p*32+c][d]: c<16 -> T_{2c}(u), c>=16 -> T_{2(c-16)+1}(u) ---
        const int p = blockIdx.x / DBLK;
        const int d = (blockIdx.x % DBLK) * 256 + threadIdx.x;
        if (d >= D_PAD) return;
        const bool live = d < D_TOTAL;
        const int dd = live ? d : 0;
        const float u = (taus[dd * 8 + c_i0[p]] - taus[dd * 8 + c_i1[p]]) * (1.0f / S_SCALE);
        float* base = Tt + (size_t)p * 32 * D_PAD + d;
        base[0] = live ? 1.f : 0.f;                       // n=0 -> c=0
        base[(size_t)16 * D_PAD] = live ? u : 0.f;        // n=1 -> c=16
        float tp = 1.f, tc = u;
        const float u2 = 2.f * u;
        for (int n = 2; n < NC; ++n) {
            float tn = u2 * tc - tp;
            tp = tc; tc = tn;
            int c = (n & 1) ? 16 + (n >> 1) : (n >> 1);
            base[(size_t)c * D_PAD] = live ? tn : 0.f;
        }
    } else {
        const int f = blockIdx.x - DBLK * NPAIR;
        const int t = threadIdx.x;
        if (t < 32) {
            const double z = (double)f * (M_PI / 512.0) * (double)S_SCALE;
            double th = M_PI * (t + 0.5) / NC;
            double ct = cos(th);
            double hs, hc;
            sincos(z * ct, &hs, &hc);
            double cp = 1.0, cc = ct, c2 = 2.0 * ct;
            sHC[0][t] = hc;      sHS[0][t] = hs;
            sHC[1][t] = hc * cc; sHS[1][t] = hs * cc;
            for (int n = 2; n < NC; ++n) {
                double cn = c2 * cc - cp;
                cp = cc; cc = cn;
                sHC[n][t] = hc * cn;
                sHS[n][t] = hs * cn;
            }
        }
        __syncthreads();
        if (t < 32) {
            const int n = (t < 16) ? 2 * t : 2 * (t - 16) + 1;
            double sum = 0.0;
            if (t < 16) { for (int j = 0; j < NC; ++j) sum += sHC[n][j]; }
            else        { for (int j = 0; j < NC; ++j) sum += sHS[n][j]; }
            double scale = (n == 0) ? (1.0 / NC) : (2.0 / NC);
            coefEO[f * 32 + t] = (float)(sum * scale);
        }
    }
}

// ---- stage A: Gp[split][bt][p*32+c] ----------------------------------------
// 128 threads: p = t&31 (p>=28 dead), sel = t>>5: sel 0,1 -> re, c0 = sel*8;
// sel 2,3 -> im, c0 = 16+(sel-2)*8. 8 coefs & NBT bt per thread (32 acc).
// Raw X chunks (NBT bt x CNT f x 72 floats) staged to LDS via global_load_lds
// DMA (wave-uniform base + lane*16; lane 0 of each participating wave always
// active -- the e<288 cut leaves lanes 0..31 of wave 0 in slot-round 2),
// double-buffered, ONE barrier per chunk. Compute reads raw (re,im) per f
// (<=2-way bank aliasing = free) and normalizes inline. Tail chunks: source
// f clamped to <=512 (in-bounds); sCall rows >= nf are zero, so the
// duplicate-f data contributes exactly 0 (finite * 0).
#define NSLOTA 3   // ceil(NBT*CNT*18 / 128) = ceil(288/128)
__global__ __launch_bounds__(128, 3) void k_stageA(
    const float* __restrict__ XXs, const float* __restrict__ coefEO,
    float* __restrict__ Gp)
{
    __shared__ float sRaw[2][NBT * CNT * 72];  // [buf][bt][fl][0..71], raw order
    __shared__ float sCall[44][32];            // whole split's coef table
    const int t     = threadIdx.x;
    const int bt0   = blockIdx.x * NBT;
    const int split = blockIdx.y;
    const int fbeg  = (F_BINS * split) / FSPLIT;
    const int fend  = (F_BINS * (split + 1)) / FSPLIT;
    const int nf     = fend - fbeg;            // 42 or 43 (>= CNT)
    const int nchunk = (nf + CNT - 1) / CNT;
    const int p   = t & 31;
    const int sel = t >> 5;
    const bool im = sel >= 2;
    const int c0  = (sel & 1) * 8 + (im ? 16 : 0);
    const int qq  = c_ptab[p < NPAIR ? p : NPAIR - 1];   // raw float idx of my pair

    // whole-split coef table; rows >= nf ZERO (their X slots hold clamped
    // duplicate-f data -> must not contribute)
    for (int e = t; e < 44 * 8; e += 128) {
        int fl = e >> 3, q = e & 7;
        float4 v = {0.f, 0.f, 0.f, 0.f};
        if (fl < nf) v = *(const float4*)&coefEO[(fbeg + fl) * 32 + q * 4];
        *(float4*)&sCall[fl][q * 4] = v;
    }

    // DMA slot precompute (chunk-invariant). Slot e in [0,288): 16B each,
    // e = bt*72 + fl*18 + q'  ->  LDS float off e*4 = bt*288 + fl*72 + q'*4.
    const float* srcp[NSLOTA];
    int fls[NSLOTA];
    #pragma unroll
    for (int s = 0; s < NSLOTA; ++s) {
        int e  = t + s * 128;
        int ec = e < 288 ? e : 0;
        int bta = ec / 72, ra = ec - bta * 72;
        fls[s]  = ra / 18;
        srcp[s] = XXs + ((size_t)(bt0 + bta) * F_BINS) * 72 + ra * 4;
    }

    float acc[NBT][8] = {};

    // issue DMA for chunk at fc into buf b. Lane 0 of each participating wave
    // is always active (e<288 cut at lane 32 of wave 0 in round s=2), so
    // readfirstlane(lds_ptr) = lane 0's -> base + lane*16 correct. Source f
    // clamped to <=512: stays in-bounds; coef row is 0 there.
    auto stage = [&](int fc, int b) {
        #pragma unroll
        for (int s = 0; s < NSLOTA; ++s) {
            if (t + s * 128 < 288) {
                const int fcs = min(fc, 512 - fls[s]);
                __builtin_amdgcn_global_load_lds(
                    (const __attribute__((address_space(1))) void*)(srcp[s] + (size_t)fcs * 72),
                    (__attribute__((address_space(3))) void*)(&sRaw[b][(t + s * 128) * 4]),
                    16, 0, 0);
            }
        }
    };
    // 1 f-group x NBT bt x 4 f x 8 c; inline normalize (1e-37 stays normal
    // under FTZ -> rsqrtf never sees +0 -> always finite)
    auto compute = [&](int fc, int b) {
        const int cbase = fc - fbeg;
        const float* rb = &sRaw[b][0];
        float4 cjA[4], cjB[4];
        #pragma unroll
        for (int j = 0; j < 4; ++j) {
            cjA[j] = *(const float4*)&sCall[cbase + j][c0];
            cjB[j] = *(const float4*)&sCall[cbase + j][c0 + 4];
        }
        #pragma unroll
        for (int bt = 0; bt < NBT; ++bt) {
            #pragma unroll
            for (int j = 0; j < 4; ++j) {
                const float* ep = rb + bt * 288 + j * 72 + qq;
                float xr = ep[0], xi = ep[36];
                float inv = rsqrtf(xr * xr + xi * xi + 1e-37f);
                float a = (im ? xi : xr) * inv;
                acc[bt][0] = fmaf(a, cjA[j].x, acc[bt][0]);
                acc[bt][1] = fmaf(a, cjA[j].y, acc[bt][1]);
                acc[bt][2] = fmaf(a, cjA[j].z, acc[bt][2]);
                acc[bt][3] = fmaf(a, cjA[j].w, acc[bt][3]);
                acc[bt][4] = fmaf(a, cjB[j].x, acc[bt][4]);
                acc[bt][5] = fmaf(a, cjB[j].y, acc[bt][5]);
                acc[bt][6] = fmaf(a, cjB[j].z, acc[bt][6]);
                acc[bt][7] = fmaf(a, cjB[j].w, acc[bt][7]);
            }
        }
    };

    stage(fbeg, 0);
    __syncthreads();          // drains DMA vmcnt + covers sCall
    for (int i = 0; i < nchunk; ++i) {
        const int b  = i & 1;
        const int fc = fbeg + i * CNT;
        if (i + 1 < nchunk) stage(fc + CNT, b ^ 1);   // in flight across compute
        compute(fc, b);
        __syncthreads();      // vmcnt(0) drain + barrier: next buf ready
    }

    if (p < NPAIR) {
        float* gsp = Gp + (size_t)split * M_TOTAL * K2;
        #pragma unroll
        for (int bt = 0; bt < NBT; ++bt) {
            float* g = gsp + (size_t)(bt0 + bt) * K2 + p * 32 + c0;
            float4 v0 = {acc[bt][0], acc[bt][1], acc[bt][2], acc[bt][3]};
            float4 v1 = {acc[bt][4], acc[bt][5], acc[bt][6], acc[bt][7]};
            *(float4*)&g[0] = v0;
            *(float4*)&g[4] = v1;
        }
    }
}

// ---- reduce the 12 f-split partials into transposed, padded Gt[k][bt] ------
// 32k x 64bt tile per block; LDS transpose -> both read and write coalesced.
__global__ __launch_bounds__(256) void k_reduceG(
    const float* __restrict__ Gp, float* __restrict__ Gt)
{
    __shared__ float sT[32][65];
    const int t   = threadIdx.x;
    const int k0  = blockIdx.x * 32;
    const int bt0 = blockIdx.y * 64;
    const size_t MK = (size_t)M_TOTAL * K2;
    #pragma unroll
    for (int i = 0; i < 8; ++i) {
        int e  = t + i * 256;
        int kl = e & 31, btl = e >> 5;
        int bt = bt0 + btl;
        float s = 0.f;
        if (bt < M_TOTAL) {
            const float* g = Gp + (size_t)bt * K2 + k0 + kl;
            #pragma unroll
            for (int pl = 0; pl < FSPLIT; ++pl) s += g[pl * MK];
        }
        sT[kl][btl] = s;
    }
    __syncthreads();
    #pragma unroll
    for (int i = 0; i < 8; ++i) {
        int e   = t + i * 256;
        int btl = e & 63, kl = e >> 6;
        Gt[(size_t)(k0 + kl) * BT_PAD + bt0 + btl] = sT[kl][btl];
    }
}

// ---- stage B: Ysp[split][1000][2688] partial of Gt^T @ Tt ------------------
// 256x64 tile, 16 rows x 4 cols per thread: 5 b128 (60 LDS-cyc) per 64 FMA
// (128 VALU-cyc) per kk -> VALU-bound with overlap. a-reads 2-way+broadcast,
// b-reads 2-way: both conflict-free.
#define BKB 32
__global__ __launch_bounds__(256, 4) void k_gemmB(
    const float* __restrict__ Gt, const float* __restrict__ Tt,
    float* __restrict__ Ysp)
{
    __shared__ float sA[BKB][260];   // [k][bt]
    __shared__ float sB[BKB][68];    // [k][d]
    const int t = threadIdx.x;
    const int row0 = blockIdx.x * 256;
    const int col0 = blockIdx.y * 64;
    const int koff = blockIdx.z * KPS;
    const int tx = t & 15;
    const int ty = t >> 4;
    float acc[16][4] = {};

    for (int k0 = 0; k0 < KPS; k0 += BKB) {
        __syncthreads();
        #pragma unroll
        for (int i = 0; i < 8; ++i) {   // A: 32k x 256bt, float4
            int e = t + i * 256;
            int kk = e >> 6, r4 = (e & 63) * 4;
            *(float4*)&sA[kk][r4] =
                *(const float4*)&Gt[(size_t)(koff + k0 + kk) * BT_PAD + row0 + r4];
        }
        #pragma unroll
        for (int i = 0; i < 2; ++i) {   // B: 32k x 64d, float4
            int e = t + i * 256;
            int kk = e >> 4, c4 = (e & 15) * 4;
            *(float4*)&sB[kk][c4] =
                *(const float4*)&Tt[(size_t)(koff + k0 + kk) * D_PAD + col0 + c4];
        }
        __syncthreads();
        #pragma unroll 8
        for (int kk = 0; kk < BKB; ++kk) {
            float4 b  = *(const float4*)&sB[kk][tx * 4];
            float4 a0 = *(const float4*)&sA[kk][ty * 16];
            float4 a1 = *(const float4*)&sA[kk][ty * 16 + 4];
            float4 a2 = *(const float4*)&sA[kk][ty * 16 + 8];
            float4 a3 = *(const float4*)&sA[kk][ty * 16 + 12];
            float av[16] = {a0.x, a0.y, a0.z, a0.w, a1.x, a1.y, a1.z, a1.w,
                            a2.x, a2.y, a2.z, a2.w, a3.x, a3.y, a3.z, a3.w};
            float bv[4] = {b.x, b.y, b.z, b.w};
            #pragma unroll
            for (int i = 0; i < 16; ++i)
                #pragma unroll
                for (int j = 0; j < 4; ++j)
                    acc[i][j] = fmaf(av[i], bv[j], acc[i][j]);
        }
    }
    float* yp = Ysp + (size_t)blockIdx.z * M_TOTAL * D_PAD;
    #pragma unroll
    for (int i = 0; i < 16; ++i) {
        int rg = row0 + ty * 16 + i;
        if (rg >= M_TOTAL) continue;
        float4 v = {acc[i][0], acc[i][1], acc[i][2], acc[i][3]};
        *(float4*)(yp + (size_t)rg * D_PAD + col0 + tx * 4) = v;
    }
}

// ---- argmax over summed K-split partials + doa gather ----------------------
__global__ __launch_bounds__(256) void k_argmax(
    const float* __restrict__ Ysp, const float* __restrict__ doas,
    float* __restrict__ out)
{
    __shared__ float sv[256];
    __shared__ int   si[256];
    const int row = blockIdx.x;
    const int tid = threadIdx.x;
    const float* y = Ysp + (size_t)row * D_PAD;
    const size_t PL = (size_t)M_TOTAL * D_PAD;
    float best = -INFINITY;
    int bi = D_TOTAL;
    for (int d = tid; d < D_TOTAL; d += 256) {
        float v = y[d] + y[d + PL] + y[d + 2 * PL] + y[d + 3 * PL];
        if (v > best) { best = v; bi = d; }
    }
    sv[tid] = best; si[tid] = bi;
    __syncthreads();
    for (int s = 128; s > 0; s >>= 1) {
        if (tid < s) {
            float v2 = sv[tid + s]; int i2 = si[tid + s];
            if (v2 > sv[tid] || (v2 == sv[tid] && i2 < si[tid])) { sv[tid] = v2; si[tid] = i2; }
        }
        __syncthreads();
    }
    if (tid == 0) {
        int idx = si[0];
        out[row * 3 + 0] = doas[idx * 3 + 0];
        out[row * 3 + 1] = doas[idx * 3 + 1];
        out[row * 3 + 2] = doas[idx * 3 + 2];
    }
}

extern "C" void kernel_launch(void* const* d_in, const int* in_sizes, int n_in,
                              void* d_out, int out_size, void* d_ws, size_t ws_size,
                              hipStream_t stream) {
    const float* XXs  = (const float*)d_in[0];  // (4,250,513,2,36) f32
    const float* taus = (const float*)d_in[1];  // (2562,8) f32
    const float* doas = (const float*)d_in[2];  // (2562,3) f32
    float* ws     = (float*)d_ws;
    float* coefEO = ws + OFF_COEF;
    float* Tt     = ws + OFF_TT;
    float* Gt     = ws + OFF_GT;
    float* Gp     = ws + OFF_GP;
    float* Ysp    = ws + OFF_YS;   // aliases Gp (consumed by k_reduceG first)

    k_init   <<<DBLK * NPAIR + F_BINS, 256, 0, stream>>>(taus, coefEO, Tt);
    k_stageA <<<dim3(M_TOTAL / NBT, FSPLIT), 128, 0, stream>>>(XXs, coefEO, Gp);
    k_reduceG<<<dim3(K2 / 32, BT_PAD / 64), 256, 0, stream>>>(Gp, Gt);
    k_gemmB  <<<dim3(BT_PAD / 256, D_PAD / 64, KSPB), 256, 0, stream>>>(Gt, Tt, Ysp);
    k_argmax <<<M_TOTAL, 256, 0, stream>>>(Ysp, doas, (float*)d_out);
}

// Round 7
// 317.351 us; speedup vs baseline: 1.0165x; 1.0165x over previous
//
#include <hip/hip_runtime.h>
#include <math.h>

// SRP-PHAT via Chebyshev factorization (degree 32; tail ~1e-7 at z_max=14.67).
// G[bt, p*32+c] = sum_f Xnorm_{re|im}[bt,f,p] * coef_c(w_f*S), then
// Ys[bt,d] = sum_k G[bt,k] * Tt[k,d]. Diagonal mic pairs dropped.
// Round 13: stageA rewritten as INDEPENDENT-WAVE workers. r0/r11/r12 all hit
// 87-91us with all pipes <40% -- the invariant was the lockstep block-wide
// barrier + vmcnt(0) drain per chunk. Now: 2 independent waves/block, each
// owns 4 bt + private double-buffered LDS staging (CNT=2), ZERO barriers in
// the main loop (per-wave inline-asm s_waitcnt vmcnt(0) + sched_barrier,
// rule 18). Lane layout: 32 pairs x 2 coef-halves; each lane does re AND im
// (halves redundant rsqrt). Grid 1500 blocks -> all waves co-resident.
// gemmB 256x64/16x4, LDS-transpose reduceG, fused k_init unchanged.

#define F_BINS  513
#define M_TOTAL 1000
#define D_TOTAL 2562
#define D_PAD   2688          // 42 * 64
#define NPAIR   28
#define NC      32
#define K2      (NPAIR * NC)  // 896
#define S_SCALE 4.67f         // |dtau| <= 4.665
#define NBT     4             // bt per WAVE
#define CNT     2             // f per chunk
#define WPB     2             // independent waves per block
#define FSPLIT  12            // stageA f-splits
#define KSPB    4             // gemmB K-splits
#define KPS     224           // K2 / KSPB
#define BT_PAD  1024          // Gt row length (bt padded)
#define DBLK    11            // ceil(D_PAD/256) for k_init ttab part
#define SLOTS   (NBT * CNT * 18)   // 144 16B DMA slots per wave-chunk

// ws layout (float offsets); total 14,094,464 floats = 56.4 MB
#define OFF_COEF 0
#define OFF_TT   16512
#define OFF_GT   (OFF_TT + (size_t)K2 * D_PAD)            // 2,424,960
#define OFF_GP   (OFF_GT + (size_t)K2 * BT_PAD)           // 3,342,464
#define OFF_YS   OFF_GP   // Ysp (4 planes = 10,752,000) aliases Gp (12 planes, same)

__device__ __constant__ int c_ptab[NPAIR] = {1,2,3,4,5,6,7, 9,10,11,12,13,14,
                                             16,17,18,19,20, 22,23,24,25,
                                             27,28,29, 31,32, 34};
__device__ __constant__ int c_i0[NPAIR] = {0,0,0,0,0,0,0, 1,1,1,1,1,1,
                                           2,2,2,2,2, 3,3,3,3, 4,4,4, 5,5, 6};
__device__ __constant__ int c_i1[NPAIR] = {1,2,3,4,5,6,7, 2,3,4,5,6,7,
                                           3,4,5,6,7, 4,5,6,7, 5,6,7, 6,7, 7};

// ---- fused init: blocks [0, DBLK*NPAIR) build Tt; blocks [.., +513) build
// coefEO[f][32] (c<16 -> cos-coeff a_{2c}(z_f); c>=16 -> sin b_{2c'+1}).
__global__ void k_init(const float* __restrict__ taus,
                       float* __restrict__ coefEO, float* __restrict__ Tt) {
    __shared__ double sHC[NC][NC + 1];
    __shared__ double sHS[NC][NC + 1];
    if (blockIdx.x < DBLK * NPAIR) {
        // ---- Tt[p*32+c][d]: c<16 -> T_{2c}(u), c>=16 -> T_{2(c-16)+1}(u) ---
        const int p = blockIdx.x / DBLK;
        const int d = (blockIdx.x % DBLK) * 256 + threadIdx.x;
        if (d >= D_PAD) return;
        const bool live = d < D_TOTAL;
        const int dd = live ? d : 0;
        const float u = (taus[dd * 8 + c_i0[p]] - taus[dd * 8 + c_i1[p]]) * (1.0f / S_SCALE);
        float* base = Tt + (size_t)p * 32 * D_PAD + d;
        base[0] = live ? 1.f : 0.f;                       // n=0 -> c=0
        base[(size_t)16 * D_PAD] = live ? u : 0.f;        // n=1 -> c=16
        float tp = 1.f, tc = u;
        const float u2 = 2.f * u;
        for (int n = 2; n < NC; ++n) {
            float tn = u2 * tc - tp;
            tp = tc; tc = tn;
            int c = (n & 1) ? 16 + (n >> 1) : (n >> 1);
            base[(size_t)c * D_PAD] = live ? tn : 0.f;
        }
    } else {
        const int f = blockIdx.x - DBLK * NPAIR;
        const int t = threadIdx.x;
        if (t < 32) {
            const double z = (double)f * (M_PI / 512.0) * (double)S_SCALE;
            double th = M_PI * (t + 0.5) / NC;
            double ct = cos(th);
            double hs, hc;
            sincos(z * ct, &hs, &hc);
            double cp = 1.0, cc = ct, c2 = 2.0 * ct;
            sHC[0][t] = hc;      sHS[0][t] = hs;
            sHC[1][t] = hc * cc; sHS[1][t] = hs * cc;
            for (int n = 2; n < NC; ++n) {
                double cn = c2 * cc - cp;
                cp = cc; cc = cn;
                sHC[n][t] = hc * cn;
                sHS[n][t] = hs * cn;
            }
        }
        __syncthreads();
        if (t < 32) {
            const int n = (t < 16) ? 2 * t : 2 * (t - 16) + 1;
            double sum = 0.0;
            if (t < 16) { for (int j = 0; j < NC; ++j) sum += sHC[n][j]; }
            else        { for (int j = 0; j < NC; ++j) sum += sHS[n][j]; }
            double scale = (n == 0) ? (1.0 / NC) : (2.0 / NC);
            coefEO[f * 32 + t] = (float)(sum * scale);
        }
    }
}

// ---- stage A: Gp[split][bt][p*32+c] ----------------------------------------
// 2 INDEPENDENT waves per block. Each wave: 4 bt rows, private double-buffered
// raw-X staging via global_load_lds (full-16B slots; slot rounds 64/64/16 --
// lane 0 of the wave always active, so the wave-uniform LDS base rule m104
// holds). Lane = pair p (l&31) x coef-half (l>>5); each lane computes both
// re (coefs half*8..+7) and im (coefs 16+half*8..+7) contributions -> 64 acc.
// Main loop has NO barriers: per-wave `s_waitcnt vmcnt(0)` (asm) +
// sched_barrier(0) [rule 18] after compute; wave drift hides DMA drain.
// Tail: source f clamped to <=512 (in-bounds); sCall rows >= nf are zero, so
// duplicate-f data contributes exactly 0 (finite * 0; rsqrtf(..+1e-37) finite).
__global__ __launch_bounds__(128, 3) void k_stageA(
    const float* __restrict__ XXs, const float* __restrict__ coefEO,
    float* __restrict__ Gp)
{
    __shared__ float sRaw[WPB][2][NBT * CNT * 72];  // per-wave 2-buf raw X
    __shared__ float sCall[44][32];                 // whole split's coef table
    const int t     = threadIdx.x;
    const int wave  = t >> 6;
    const int lane  = t & 63;
    const int split = blockIdx.y;
    const int fbeg  = (F_BINS * split) / FSPLIT;
    const int fend  = (F_BINS * (split + 1)) / FSPLIT;
    const int nf     = fend - fbeg;            // 42 or 43
    const int nchunk = (nf + CNT - 1) / CNT;   // 21 or 22
    const int btg0  = (blockIdx.x * WPB + wave) * NBT;
    const int p     = lane & 31;
    const int half  = lane >> 5;
    const int qq    = c_ptab[p < NPAIR ? p : NPAIR - 1];

    // whole-split coef table (cooperative, both waves); rows >= nf ZERO
    for (int e = t; e < 44 * 8; e += 128) {
        int fl = e >> 3, q = e & 7;
        float4 v = {0.f, 0.f, 0.f, 0.f};
        if (fl < nf) v = *(const float4*)&coefEO[(fbeg + fl) * 32 + q * 4];
        *(float4*)&sCall[fl][q * 4] = v;
    }

    // DMA slot precompute (chunk-invariant). Slot e in [0,144): 16B each,
    // e = bt*36 + fl*18 + q' -> LDS float off e*4 = bt*144 + fl*72 + q'*4.
    const float* srcp[3];
    int fls[3];
    #pragma unroll
    for (int s = 0; s < 3; ++s) {
        int e  = lane + s * 64;
        int ec = e < SLOTS ? e : 0;
        int bta = ec / 36, rem = ec - bta * 36;
        fls[s]  = rem / 18;   // 0 or 1
        srcp[s] = XXs + ((size_t)(btg0 + bta) * F_BINS) * 72 + rem * 4;
    }

    float acc[NBT][16] = {};

    // issue this wave's DMA for chunk at fc into its buf b. Rounds: s0,s1
    // full-wave; s2 lanes 0..15 (first active lane = 0 -> LDS base correct).
    auto stage = [&](int fc, int b) {
        float* dst = &sRaw[wave][b][0];
        #pragma unroll
        for (int s = 0; s < 3; ++s) {
            if (s < 2 || lane < 16) {
                const int fcs = min(fc, 512 - fls[s]);   // clamp: f <= 512
                __builtin_amdgcn_global_load_lds(
                    (const __attribute__((address_space(1))) void*)(srcp[s] + (size_t)fcs * 72),
                    (__attribute__((address_space(3))) void*)(dst + (lane + s * 64) * 4),
                    16, 0, 0);
            }
        }
    };

    // 2 f x 4 bt x (re 8 + im 8) FMAs; inline normalize (1e-37 stays normal
    // under FTZ -> rsqrtf never sees +0 -> always finite)
    auto compute = [&](int fc, int b) {
        const float* rb = &sRaw[wave][b][0];
        #pragma unroll
        for (int fl = 0; fl < CNT; ++fl) {
            const int cr = fc - fbeg + fl;
            float4 cA0 = *(const float4*)&sCall[cr][half * 8];
            float4 cA1 = *(const float4*)&sCall[cr][half * 8 + 4];
            float4 cB0 = *(const float4*)&sCall[cr][16 + half * 8];
            float4 cB1 = *(const float4*)&sCall[cr][16 + half * 8 + 4];
            #pragma unroll
            for (int bt = 0; bt < NBT; ++bt) {
                const float* ep = rb + bt * (CNT * 72) + fl * 72 + qq;
                float xr = ep[0], xi = ep[36];
                float inv = rsqrtf(xr * xr + xi * xi + 1e-37f);
                float ar = xr * inv, ai = xi * inv;
                acc[bt][0]  = fmaf(ar, cA0.x, acc[bt][0]);
                acc[bt][1]  = fmaf(ar, cA0.y, acc[bt][1]);
                acc[bt][2]  = fmaf(ar, cA0.z, acc[bt][2]);
                acc[bt][3]  = fmaf(ar, cA0.w, acc[bt][3]);
                acc[bt][4]  = fmaf(ar, cA1.x, acc[bt][4]);
                acc[bt][5]  = fmaf(ar, cA1.y, acc[bt][5]);
                acc[bt][6]  = fmaf(ar, cA1.z, acc[bt][6]);
                acc[bt][7]  = fmaf(ar, cA1.w, acc[bt][7]);
                acc[bt][8]  = fmaf(ai, cB0.x, acc[bt][8]);
                acc[bt][9]  = fmaf(ai, cB0.y, acc[bt][9]);
                acc[bt][10] = fmaf(ai, cB0.z, acc[bt][10]);
                acc[bt][11] = fmaf(ai, cB0.w, acc[bt][11]);
                acc[bt][12] = fmaf(ai, cB1.x, acc[bt][12]);
                acc[bt][13] = fmaf(ai, cB1.y, acc[bt][13]);
                acc[bt][14] = fmaf(ai, cB1.z, acc[bt][14]);
                acc[bt][15] = fmaf(ai, cB1.w, acc[bt][15]);
            }
        }
    };

    stage(fbeg, 0);
    __syncthreads();   // sCall ready (both waves) + initial DMA drained
    for (int i = 0; i < nchunk; ++i) {
        const int b  = i & 1;
        const int fc = fbeg + i * CNT;
        if (i + 1 < nchunk) stage(fc + CNT, b ^ 1);   // in flight across compute
        compute(fc, b);
        asm volatile("s_waitcnt vmcnt(0)" ::: "memory");  // own DMA done
        __builtin_amdgcn_sched_barrier(0);                // rule 18 fence
    }

    if (p < NPAIR) {
        float* gsp = Gp + (size_t)split * M_TOTAL * K2;
        #pragma unroll
        for (int bt = 0; bt < NBT; ++bt) {
            float* g = gsp + (size_t)(btg0 + bt) * K2 + p * 32 + half * 8;
            float4 v0 = {acc[bt][0],  acc[bt][1],  acc[bt][2],  acc[bt][3]};
            float4 v1 = {acc[bt][4],  acc[bt][5],  acc[bt][6],  acc[bt][7]};
            float4 v2 = {acc[bt][8],  acc[bt][9],  acc[bt][10], acc[bt][11]};
            float4 v3 = {acc[bt][12], acc[bt][13], acc[bt][14], acc[bt][15]};
            *(float4*)&g[0]  = v0;   // c = half*8 + 0..3
            *(float4*)&g[4]  = v1;   // c = half*8 + 4..7
            *(float4*)&g[16] = v2;   // c = 16 + half*8 + 0..3
            *(float4*)&g[20] = v3;   // c = 16 + half*8 + 4..7
        }
    }
}

// ---- reduce the 12 f-split partials into transposed, padded Gt[k][bt] ------
// 32k x 64bt tile per block; LDS transpose -> both read and write coalesced.
__global__ __launch_bounds__(256) void k_reduceG(
    const float* __restrict__ Gp, float* __restrict__ Gt)
{
    __shared__ float sT[32][65];
    const int t   = threadIdx.x;
    const int k0  = blockIdx.x * 32;
    const int bt0 = blockIdx.y * 64;
    const size_t MK = (size_t)M_TOTAL * K2;
    #pragma unroll
    for (int i = 0; i < 8; ++i) {
        int e  = t + i * 256;
        int kl = e & 31, btl = e >> 5;
        int bt = bt0 + btl;
        float s = 0.f;
        if (bt < M_TOTAL) {
            const float* g = Gp + (size_t)bt * K2 + k0 + kl;
            #pragma unroll
            for (int pl = 0; pl < FSPLIT; ++pl) s += g[pl * MK];
        }
        sT[kl][btl] = s;
    }
    __syncthreads();
    #pragma unroll
    for (int i = 0; i < 8; ++i) {
        int e   = t + i * 256;
        int btl = e & 63, kl = e >> 6;
        Gt[(size_t)(k0 + kl) * BT_PAD + bt0 + btl] = sT[kl][btl];
    }
}

// ---- stage B: Ysp[split][1000][2688] partial of Gt^T @ Tt ------------------
// 256x64 tile, 16 rows x 4 cols per thread: 5 b128 (60 LDS-cyc) per 64 FMA
// (128 VALU-cyc) per kk -> VALU-bound with overlap. a-reads 2-way+broadcast,
// b-reads 2-way: both conflict-free.
#define BKB 32
__global__ __launch_bounds__(256, 4) void k_gemmB(
    const float* __restrict__ Gt, const float* __restrict__ Tt,
    float* __restrict__ Ysp)
{
    __shared__ float sA[BKB][260];   // [k][bt]
    __shared__ float sB[BKB][68];    // [k][d]
    const int t = threadIdx.x;
    const int row0 = blockIdx.x * 256;
    const int col0 = blockIdx.y * 64;
    const int koff = blockIdx.z * KPS;
    const int tx = t & 15;
    const int ty = t >> 4;
    float acc[16][4] = {};

    for (int k0 = 0; k0 < KPS; k0 += BKB) {
        __syncthreads();
        #pragma unroll
        for (int i = 0; i < 8; ++i) {   // A: 32k x 256bt, float4
            int e = t + i * 256;
            int kk = e >> 6, r4 = (e & 63) * 4;
            *(float4*)&sA[kk][r4] =
                *(const float4*)&Gt[(size_t)(koff + k0 + kk) * BT_PAD + row0 + r4];
        }
        #pragma unroll
        for (int i = 0; i < 2; ++i) {   // B: 32k x 64d, float4
            int e = t + i * 256;
            int kk = e >> 4, c4 = (e & 15) * 4;
            *(float4*)&sB[kk][c4] =
                *(const float4*)&Tt[(size_t)(koff + k0 + kk) * D_PAD + col0 + c4];
        }
        __syncthreads();
        #pragma unroll 8
        for (int kk = 0; kk < BKB; ++kk) {
            float4 b  = *(const float4*)&sB[kk][tx * 4];
            float4 a0 = *(const float4*)&sA[kk][ty * 16];
            float4 a1 = *(const float4*)&sA[kk][ty * 16 + 4];
            float4 a2 = *(const float4*)&sA[kk][ty * 16 + 8];
            float4 a3 = *(const float4*)&sA[kk][ty * 16 + 12];
            float av[16] = {a0.x, a0.y, a0.z, a0.w, a1.x, a1.y, a1.z, a1.w,
                            a2.x, a2.y, a2.z, a2.w, a3.x, a3.y, a3.z, a3.w};
            float bv[4] = {b.x, b.y, b.z, b.w};
            #pragma unroll
            for (int i = 0; i < 16; ++i)
                #pragma unroll
                for (int j = 0; j < 4; ++j)
                    acc[i][j] = fmaf(av[i], bv[j], acc[i][j]);
        }
    }
    float* yp = Ysp + (size_t)blockIdx.z * M_TOTAL * D_PAD;
    #pragma unroll
    for (int i = 0; i < 16; ++i) {
        int rg = row0 + ty * 16 + i;
        if (rg >= M_TOTAL) continue;
        float4 v = {acc[i][0], acc[i][1], acc[i][2], acc[i][3]};
        *(float4*)(yp + (size_t)rg * D_PAD + col0 + tx * 4) = v;
    }
}

// ---- argmax over summed K-split partials + doa gather ----------------------
__global__ __launch_bounds__(256) void k_argmax(
    const float* __restrict__ Ysp, const float* __restrict__ doas,
    float* __restrict__ out)
{
    __shared__ float sv[256];
    __shared__ int   si[256];
    const int row = blockIdx.x;
    const int tid = threadIdx.x;
    const float* y = Ysp + (size_t)row * D_PAD;
    const size_t PL = (size_t)M_TOTAL * D_PAD;
    float best = -INFINITY;
    int bi = D_TOTAL;
    for (int d = tid; d < D_TOTAL; d += 256) {
        float v = y[d] + y[d + PL] + y[d + 2 * PL] + y[d + 3 * PL];
        if (v > best) { best = v; bi = d; }
    }
    sv[tid] = best; si[tid] = bi;
    __syncthreads();
    for (int s = 128; s > 0; s >>= 1) {
        if (tid < s) {
            float v2 = sv[tid + s]; int i2 = si[tid + s];
            if (v2 > sv[tid] || (v2 == sv[tid] && i2 < si[tid])) { sv[tid] = v2; si[tid] = i2; }
        }
        __syncthreads();
    }
    if (tid == 0) {
        int idx = si[0];
        out[row * 3 + 0] = doas[idx * 3 + 0];
        out[row * 3 + 1] = doas[idx * 3 + 1];
        out[row * 3 + 2] = doas[idx * 3 + 2];
    }
}

extern "C" void kernel_launch(void* const* d_in, const int* in_sizes, int n_in,
                              void* d_out, int out_size, void* d_ws, size_t ws_size,
                              hipStream_t stream) {
    const float* XXs  = (const float*)d_in[0];  // (4,250,513,2,36) f32
    const float* taus = (const float*)d_in[1];  // (2562,8) f32
    const float* doas = (const float*)d_in[2];  // (2562,3) f32
    float* ws     = (float*)d_ws;
    float* coefEO = ws + OFF_COEF;
    float* Tt     = ws + OFF_TT;
    float* Gt     = ws + OFF_GT;
    float* Gp     = ws + OFF_GP;
    float* Ysp    = ws + OFF_YS;   // aliases Gp (consumed by k_reduceG first)

    k_init   <<<DBLK * NPAIR + F_BINS, 256, 0, stream>>>(taus, coefEO, Tt);
    k_stageA <<<dim3(M_TOTAL / (NBT * WPB), FSPLIT), 128, 0, stream>>>(XXs, coefEO, Gp);
    k_reduceG<<<dim3(K2 / 32, BT_PAD / 64), 256, 0, stream>>>(Gp, Gt);
    k_gemmB  <<<dim3(BT_PAD / 256, D_PAD / 64, KSPB), 256, 0, stream>>>(Gt, Tt, Ysp);
    k_argmax <<<M_TOTAL, 256, 0, stream>>>(Ysp, doas, (float*)d_out);
}